// Round 4
// baseline (136.745 us; speedup 1.0000x reference)
//
#include <hip/hip_runtime.h>
#include <hip/hip_bf16.h>
#include <math.h>

typedef __attribute__((ext_vector_type(8))) short  short8;    // 8 bf16 = 4 VGPRs
typedef __attribute__((ext_vector_type(4))) float  floatx4;   // MFMA C/D

#define MFMA16(a, b, c) __builtin_amdgcn_mfma_f32_16x16x32_bf16(a, b, c, 0, 0, 0)

constexpr int NSEQ = 2048;
constexpr int DIN  = 768;
constexpr int NH   = 12;
constexpr float QSCALE = 0.18033688011112042f;  // log2(e)/8
constexpr int PART_STRIDE = 64 * 64 + 64;       // O^T tile + l row (floats)
constexpr size_t HB_ELEMS = (size_t)2 * NH * NSEQ * 64;

__device__ __forceinline__ ushort f2bf(float f) {   // RNE fp32 -> bf16
    unsigned u = __float_as_uint(f);
    u += 0x7FFF + ((u >> 16) & 1);
    return (ushort)(u >> 16);
}
__device__ __forceinline__ float bf2f(ushort u) {
    return __uint_as_float(((unsigned)u) << 16);
}
__device__ __forceinline__ unsigned pk2(float a, float b) {   // packed cvt
    __hip_bfloat162 h = __float22bfloat162_rn(float2{a, b});
    return *(unsigned*)&h;
}
__device__ __forceinline__ short8 cvt8(float4 a, float4 b) {
    union { short8 s; unsigned u[4]; } r;
    r.u[0] = pk2(a.x, a.y); r.u[1] = pk2(a.z, a.w);
    r.u[2] = pk2(b.x, b.y); r.u[3] = pk2(b.z, b.w);
    return r.s;
}

// -----------------------------------------------------------------------------
// Kernel 1: h = x @ Wq^T, fp32->bf16 cvt fused into staging (packed cvt).
// BM=64 x BN=128, BK=64, 384 blocks, register prefetch. h[b*NH+head][q][64] bf16.
// -----------------------------------------------------------------------------
__global__ __launch_bounds__(256, 3)
void qkv_mfma(const float* __restrict__ x, const float* __restrict__ Wq,
              ushort* __restrict__ h)
{
    __shared__ ushort As[64 * 72];
    __shared__ ushort Bs[128 * 72];

    const int tid  = threadIdx.x;
    const int w    = tid >> 6;
    const int lane = tid & 63;
    const int m    = lane & 15;
    const int quad = lane >> 4;
    const int r0   = blockIdx.x * 64;
    const int c0   = blockIdx.y * 128;
    const int mrow0 = (w & 1) * 32;
    const int ncol0 = (w >> 1) * 64;

    const int xr = tid >> 2, xc = (tid & 3) * 16;   // X stager: 16 floats
    const int wr = tid >> 1, wc = (tid & 1) * 32;   // W stager: 32 floats

    floatx4 C[2][4] = {};
    float4 xa[4], wa[8];

    #pragma unroll
    for (int j = 0; j < 4; ++j)
        xa[j] = *(const float4*)(x + (size_t)(r0 + xr) * DIN + xc + j * 4);
    #pragma unroll
    for (int j = 0; j < 8; ++j)
        wa[j] = *(const float4*)(Wq + (size_t)(c0 + wr) * DIN + wc + j * 4);

    for (int kk = 0; kk < 12; ++kk) {
        __syncthreads();
        *(short8*)&As[xr * 72 + xc]     = cvt8(xa[0], xa[1]);
        *(short8*)&As[xr * 72 + xc + 8] = cvt8(xa[2], xa[3]);
        #pragma unroll
        for (int v = 0; v < 4; ++v)
            *(short8*)&Bs[wr * 72 + wc + v * 8] = cvt8(wa[v * 2], wa[v * 2 + 1]);
        if (kk < 11) {
            const int k0 = (kk + 1) * 64;
            #pragma unroll
            for (int j = 0; j < 4; ++j)
                xa[j] = *(const float4*)(x + (size_t)(r0 + xr) * DIN + k0 + xc + j * 4);
            #pragma unroll
            for (int j = 0; j < 8; ++j)
                wa[j] = *(const float4*)(Wq + (size_t)(c0 + wr) * DIN + k0 + wc + j * 4);
        }
        __syncthreads();

        #pragma unroll
        for (int kt2 = 0; kt2 < 2; ++kt2) {
            short8 a0 = *(const short8*)&As[(mrow0 + m)      * 72 + kt2 * 32 + quad * 8];
            short8 a1 = *(const short8*)&As[(mrow0 + 16 + m) * 72 + kt2 * 32 + quad * 8];
            #pragma unroll
            for (int nt = 0; nt < 4; ++nt) {
                short8 bf = *(const short8*)&Bs[(ncol0 + nt * 16 + m) * 72 + kt2 * 32 + quad * 8];
                C[0][nt] = MFMA16(a0, bf, C[0][nt]);
                C[1][nt] = MFMA16(a1, bf, C[1][nt]);
            }
        }
    }

    #pragma unroll
    for (int mt = 0; mt < 2; ++mt)
        #pragma unroll
        for (int nt = 0; nt < 4; ++nt) {
            int cg = c0 + ncol0 + nt * 16 + m;
            int head = cg >> 6, d = cg & 63;
            #pragma unroll
            for (int r = 0; r < 4; ++r) {
                int rg = r0 + mrow0 + mt * 16 + quad * 4 + r;
                int b = rg >> 11, q = rg & 2047;
                h[((size_t)(b * NH + head) * NSEQ + q) * 64 + d] = f2bf(C[mt][nt][r]);
            }
        }
}

// -----------------------------------------------------------------------------
// Kernel 2: split-K causal flash attention. Work unit = (bh, 64-q strip qt,
// k-chunk kc of 8 k-tiles). Partial (O^T, l) are ADDITIVE (no-max softmax), so
// chunks write fp32 partials to ws; 1-chunk strips (qt<8) normalize + write out
// directly. l computed by MFMA via a ones-row appended to V^T. 1920 blocks.
// -----------------------------------------------------------------------------
__global__ __launch_bounds__(256, 4)
void attn_mfma(const ushort* __restrict__ h, float* __restrict__ parts,
               float* __restrict__ out)
{
    __shared__ ushort Ks[64 * 72];      // [key][d]
    __shared__ ushort Vt[80 * 72];      // [d][key], row 64 = ones (l via MFMA)
    __shared__ ushort Ps[4 * 16 * 72];  // per-wave P [q][key]

    const int tid  = threadIdx.x;
    const int w    = tid >> 6;
    const int lane = tid & 63;
    const int m    = lane & 15;
    const int quad = lane >> 4;

    // unit -> (qt, kc), heavy chunks dispatched first
    const int u  = blockIdx.x;
    const int bh = blockIdx.y;
    int qt, kc;
    if (u < 32)      { qt = 24 + (u >> 2); kc = u & 3; }
    else if (u < 56) { int v = u - 32; int q3 = v / 3; qt = 16 + q3; kc = v - q3 * 3; }
    else if (u < 72) { int v = u - 56; qt = 8 + (v >> 1); kc = v & 1; }
    else             { qt = u - 72; kc = 0; }
    const int nc  = (qt + 8) >> 3;
    const int kt0 = kc * 8;
    const int kt1 = min(kc * 8 + 8, qt + 1);
    const int q0  = qt * 64;
    const int wq  = q0 + w * 16;
    const ushort* __restrict__ Hh = h + (size_t)bh * NSEQ * 64;

    if (tid < 32) ((unsigned*)&Vt[64 * 72])[tid] = 0x3F803F80u;  // ones row

    // Q fragments (B-operand), pre-scaled by log2(e)/8
    short8 qa[2];
    #pragma unroll
    for (int kt2 = 0; kt2 < 2; ++kt2) {
        short8 raw = *(const short8*)(Hh + (size_t)(wq + m) * 64 + kt2 * 32 + quad * 8);
        #pragma unroll
        for (int j = 0; j < 8; ++j)
            qa[kt2][j] = (short)f2bf(bf2f((ushort)raw[j]) * QSCALE);
    }

    floatx4 O[4] = {};                  // O^T: d = mt*16+quad*4+r, q = m
    floatx4 O5 = {};                    // l tile (row 0 = ones . P^T)
    ushort* Psw = Ps + w * 16 * 72;

    const int kr2  = (tid & 31) * 2;
    const int part = tid >> 5;

    short8 a0, a1;
    {
        const ushort* src = Hh + (size_t)(kt0 * 64 + kr2) * 64 + part * 8;
        a0 = *(const short8*)src;
        a1 = *(const short8*)(src + 64);
    }

    for (int kt = kt0; kt < kt1; ++kt) {
        __syncthreads();
        union { short8 v; ushort u[8]; } ua, ub;
        ua.v = a0; ub.v = a1;
        *(short8*)&Ks[kr2       * 72 + part * 8] = a0;
        *(short8*)&Ks[(kr2 + 1) * 72 + part * 8] = a1;
        #pragma unroll
        for (int i = 0; i < 8; ++i) {
            unsigned pk = (unsigned)ua.u[i] | ((unsigned)ub.u[i] << 16);
            *(unsigned*)&Vt[(part * 8 + i) * 72 + kr2] = pk;
        }
        if (kt + 1 < kt1) {
            const ushort* src = Hh + (size_t)((kt + 1) * 64 + kr2) * 64 + part * 8;
            a0 = *(const short8*)src;
            a1 = *(const short8*)(src + 64);
        }
        __syncthreads();

        // ---- S^T = K Q^T ----
        floatx4 S[4] = {};
        #pragma unroll
        for (int kt2 = 0; kt2 < 2; ++kt2)
            #pragma unroll
            for (int mt = 0; mt < 4; ++mt) {
                short8 ka = *(const short8*)&Ks[(mt * 16 + m) * 72 + kt2 * 32 + quad * 8];
                S[mt] = MFMA16(ka, qa[kt2], S[mt]);
            }

        // ---- exp2 + packed P write ----
        const int kb = kt * 64;
        if (kt == qt) {                 // diagonal: causal mask
            #pragma unroll
            for (int mt = 0; mt < 4; ++mt) {
                float p[4];
                #pragma unroll
                for (int r = 0; r < 4; ++r) {
                    int kg = kb + mt * 16 + quad * 4 + r;
                    p[r] = (kg <= wq + m) ? __builtin_amdgcn_exp2f(S[mt][r]) : 0.0f;
                }
                uint2 pw = {pk2(p[0], p[1]), pk2(p[2], p[3])};
                *(uint2*)&Psw[m * 72 + mt * 16 + quad * 4] = pw;
            }
        } else {
            #pragma unroll
            for (int mt = 0; mt < 4; ++mt) {
                float p[4];
                #pragma unroll
                for (int r = 0; r < 4; ++r)
                    p[r] = __builtin_amdgcn_exp2f(S[mt][r]);
                uint2 pw = {pk2(p[0], p[1]), pk2(p[2], p[3])};
                *(uint2*)&Psw[m * 72 + mt * 16 + quad * 4] = pw;
            }
        }

        // ---- O^T += V^T P^T ; l += ones . P^T ----
        #pragma unroll
        for (int kt2 = 0; kt2 < 2; ++kt2) {
            short8 pb = *(const short8*)&Psw[m * 72 + kt2 * 32 + quad * 8];
            #pragma unroll
            for (int mt = 0; mt < 4; ++mt) {
                short8 va = *(const short8*)&Vt[(mt * 16 + m) * 72 + kt2 * 32 + quad * 8];
                O[mt] = MFMA16(va, pb, O[mt]);
            }
            short8 v5 = *(const short8*)&Vt[(64 + m) * 72 + kt2 * 32 + quad * 8];
            O5 = MFMA16(v5, pb, O5);
        }
    }

    // l(q=m) lives in lane (quad0, m), reg 0 -> broadcast
    float lval = __shfl(O5[0], m);

    if (nc == 1) {                      // full k-range in this block
        float linv = 1.0f / lval;
        #pragma unroll
        for (int mt = 0; mt < 4; ++mt)
            #pragma unroll
            for (int r = 0; r < 4; ++r) {
                int d = mt * 16 + quad * 4 + r;
                out[((size_t)bh * 64 + d) * NSEQ + q0 + w * 16 + m] = O[mt][r] * linv;
            }
    } else {                            // partial -> ws
        float* P = parts + (size_t)((bh * 32 + qt) * 4 + kc) * PART_STRIDE;
        #pragma unroll
        for (int mt = 0; mt < 4; ++mt)
            #pragma unroll
            for (int r = 0; r < 4; ++r)
                P[(mt * 16 + quad * 4 + r) * 64 + w * 16 + m] = O[mt][r];
        if (quad == 0) P[4096 + w * 16 + m] = O5[0];
    }
}

// -----------------------------------------------------------------------------
// Kernel 3: combine partials for qt >= 8: out = (sum_c O_c) / (sum_c l_c).
// -----------------------------------------------------------------------------
__global__ __launch_bounds__(256)
void combine(const float* __restrict__ parts, float* __restrict__ out)
{
    const int qt = 8 + blockIdx.x;      // 8..31
    const int bh = blockIdx.y;
    const int nc = (qt + 8) >> 3;
    const float* base = parts + (size_t)((bh * 32 + qt) * 4) * PART_STRIDE;

    __shared__ float linv[64];
    const int tid = threadIdx.x;
    if (tid < 64) {
        float s = 0.0f;
        for (int c = 0; c < nc; ++c) s += base[c * PART_STRIDE + 4096 + tid];
        linv[tid] = 1.0f / s;
    }
    __syncthreads();

    const int d  = tid >> 2;
    const int qo = (tid & 3) * 16;
    float4 acc[4] = {};
    for (int c = 0; c < nc; ++c) {
        const float4* p = (const float4*)(base + c * PART_STRIDE + d * 64 + qo);
        #pragma unroll
        for (int j = 0; j < 4; ++j) {
            float4 v = p[j];
            acc[j].x += v.x; acc[j].y += v.y; acc[j].z += v.z; acc[j].w += v.w;
        }
    }
    float* dst = out + ((size_t)bh * 64 + d) * NSEQ + qt * 64 + qo;
    #pragma unroll
    for (int j = 0; j < 4; ++j) {
        float4 lv = *(const float4*)&linv[qo + j * 4];
        float4 o = make_float4(acc[j].x * lv.x, acc[j].y * lv.y,
                               acc[j].z * lv.z, acc[j].w * lv.w);
        *(float4*)(dst + j * 4) = o;
    }
}

extern "C" void kernel_launch(void* const* d_in, const int* in_sizes, int n_in,
                              void* d_out, int out_size, void* d_ws, size_t ws_size,
                              hipStream_t stream)
{
    (void)in_sizes; (void)n_in; (void)out_size; (void)ws_size;
    const float* x  = (const float*)d_in[0];
    const float* Wq = (const float*)d_in[1];
    float* out = (float*)d_out;

    ushort* hb    = (ushort*)d_ws;                       // 6.29 MB
    float*  partb = (float*)((char*)d_ws + HB_ELEMS * sizeof(ushort)); // 51 MB

    qkv_mfma<<<dim3(64, 6),  dim3(256), 0, stream>>>(x, Wq, hb);
    attn_mfma<<<dim3(80, 24), dim3(256), 0, stream>>>(hb, partb, out);
    combine<<<dim3(24, 24),  dim3(256), 0, stream>>>(partb, out);
}